// Round 3
// baseline (560.372 us; speedup 1.0000x reference)
//
#include <hip/hip_runtime.h>

// Problem constants
#define BB 16
#define SS 8192
#define DD 512   // Q_DIM == K_DIM == ATTN_DIM

typedef float  f32x4  __attribute__((ext_vector_type(4)));
typedef __bf16 bf16x8 __attribute__((ext_vector_type(8)));
typedef __bf16 bf16x4 __attribute__((ext_vector_type(4)));

__device__ __forceinline__ void cvt_store_bf4(unsigned short* dst, f32x4 v) {
    bf16x4 o;
    o.x = (__bf16)v.x; o.y = (__bf16)v.y; o.z = (__bf16)v.z; o.w = (__bf16)v.w;
    *(bf16x4*)dst = o;   // 8-byte LDS store
}

__device__ __forceinline__ float tanh_fast(float x) {
    float e2 = __expf(2.0f * x);
    return 1.0f - 2.0f / (e2 + 1.0f);   // -> +/-1 correctly as e2 -> inf/0
}

// ---------------------------------------------------------------------------
// Kernel 1: qproj = query @ Wq  (fp32),  WkT[n][k] = bf16(Wk[k][n])
// ---------------------------------------------------------------------------
__global__ void prep_kernel(const float* __restrict__ query, const float* __restrict__ Wq,
                            const float* __restrict__ Wk, float* __restrict__ qproj,
                            unsigned short* __restrict__ WkT)
{
    const int bid = blockIdx.x, t = threadIdx.x;
    if (bid < DD) {                       // one block per output row n of WkT
        const int n = bid;
        for (int k = t; k < DD; k += 256) {
            __bf16 h = (__bf16)Wk[k * DD + n];
            WkT[n * DD + k] = __builtin_bit_cast(unsigned short, h);
        }
    } else {                              // blocks 512..543: qproj, one output/thread
        const int idx = (bid - DD) * 256 + t;   // 0..8191
        const int b = idx >> 9;
        const int n = idx & 511;
        const float* q  = query + b * DD;
        const float* wp = Wq + n;
        float acc = 0.0f;
#pragma unroll 8
        for (int k = 0; k < DD; ++k)
            acc = fmaf(q[k], wp[(size_t)k * DD], acc);
        qproj[b * DD + n] = acc;
    }
}

// ---------------------------------------------------------------------------
// Kernel 2 (fused): scores + block-local softmax stats + context partial.
// Structure: stage full 64x512 keys tile to LDS ONCE (bf16, fragment-major),
// single barrier, then a BARRIER-FREE K-loop with A from LDS and B fragments
// loaded directly from global WkT (512 KB, L2-resident) into registers.
// ---------------------------------------------------------------------------
__global__ __launch_bounds__(256, 2) void fused_kernel(
    const float* __restrict__ keys, const unsigned short* __restrict__ WkT,
    const float* __restrict__ qproj, const float* __restrict__ vvec,
    const int* __restrict__ mask, float* __restrict__ e_ws,
    float* __restrict__ cpart, float2* __restrict__ ml_ws)
{
    __shared__ unsigned short ksA[16 * 2048];     // [j-chunk][i-tile][lane][8] = 64 KB
    __shared__ float sm_part[4][64];
    __shared__ float w_sh[64];
    __shared__ f32x4 red[128];

    const int tid  = threadIdx.x;
    const int w    = tid >> 6;        // wave 0..3 -> n slice [128w, 128w+128)
    const int lane = tid & 63;
    const int ml   = lane & 15;
    const int quad = lane >> 4;
    const int bid  = blockIdx.x;
    const int b    = bid >> 7;                 // 128 s-chunks per b
    const int chunk = bid & 127;
    const int s0   = chunk << 6;

    // --- stage keys tile (64 rows x 512 k) fp32 -> bf16, fragment-major, ONCE ---
    // thread t covers row m = t>>2; float4 #(t&3) and #(t&3)+4 of each 32-k chunk
    const int m  = tid >> 2;
    const int q4 = tid & 3;
    const float* krow = keys + ((size_t)(b * SS + s0 + m)) * DD + q4 * 4;
    const int it  = m >> 4;
    const int g0  = q4 >> 1;
    const int j0  = (q4 & 1) * 4;
    const int base0 = it * 512 + ((m & 15) + 16 * g0)       * 8 + j0;
    const int base1 = it * 512 + ((m & 15) + 16 * (g0 + 2)) * 8 + j0;
#pragma unroll 4
    for (int j = 0; j < 16; ++j) {
        f32x4 k0 = *(const f32x4*)(krow + j * 32);
        f32x4 k1 = *(const f32x4*)(krow + j * 32 + 16);
        cvt_store_bf4(&ksA[j * 2048 + base0], k0);
        cvt_store_bf4(&ksA[j * 2048 + base1], k1);
    }
    __syncthreads();          // the ONLY barrier before the epilogue

    // --- barrier-free K loop ---
    // B fragment for (jn, j): WkT[n=128w+16jn+ml][k=32j+8*quad .. +8]
    const unsigned short* wb = WkT + (size_t)(w * 128 + ml) * DD + quad * 8;

    f32x4 acc[4][8];
#pragma unroll
    for (int i = 0; i < 4; ++i)
#pragma unroll
        for (int jn = 0; jn < 8; ++jn) acc[i][jn] = (f32x4){0.f, 0.f, 0.f, 0.f};

#pragma unroll 2
    for (int j = 0; j < 16; ++j) {
        bf16x8 af[4];
#pragma unroll
        for (int i = 0; i < 4; ++i)
            af[i] = *(const bf16x8*)&ksA[j * 2048 + (i * 64 + lane) * 8];
#pragma unroll
        for (int jn = 0; jn < 8; ++jn) {
            bf16x8 bfr = *(const bf16x8*)(wb + (size_t)jn * 16 * DD + j * 32);
#pragma unroll
            for (int i = 0; i < 4; ++i)
                acc[i][jn] = __builtin_amdgcn_mfma_f32_16x16x32_bf16(af[i], bfr, acc[i][jn], 0, 0, 0);
        }
    }

    // epilogue: e-partials.  C layout: row = quad*4 + reg, col = ml
    float qv[8], vv[8];
#pragma unroll
    for (int jn = 0; jn < 8; ++jn) {
        const int n = w * 128 + jn * 16 + ml;
        qv[jn] = qproj[b * DD + n];
        vv[jn] = vvec[n];
    }
#pragma unroll
    for (int i = 0; i < 4; ++i) {
#pragma unroll
        for (int r = 0; r < 4; ++r) {
            float s = 0.0f;
#pragma unroll
            for (int jn = 0; jn < 8; ++jn) {
                float xx = acc[i][jn][r] + qv[jn];
                s += tanh_fast(xx) * vv[jn];
            }
            s += __shfl_xor(s, 1, 64);
            s += __shfl_xor(s, 2, 64);
            s += __shfl_xor(s, 4, 64);
            s += __shfl_xor(s, 8, 64);
            if (ml == 0) sm_part[w][i * 16 + quad * 4 + r] = s;
        }
    }
    __syncthreads();

    // block-local softmax stats (one wave: tid < 64, each thread one s-row)
    if (tid < 64) {
        float e = sm_part[0][tid] + sm_part[1][tid] + sm_part[2][tid] + sm_part[3][tid];
        const int mk = mask[b * SS + s0 + tid];
        if (mk == 0) e = -3.402823466e38f;
        e_ws[(size_t)b * SS + s0 + tid] = e;
        float mx = e;
#pragma unroll
        for (int off = 32; off >= 1; off >>= 1) mx = fmaxf(mx, __shfl_xor(mx, off, 64));
        float wv = (mk == 0) ? 0.0f : __expf(e - mx);
        float l  = wv;
#pragma unroll
        for (int off = 32; off >= 1; off >>= 1) l += __shfl_xor(l, off, 64);
        w_sh[tid] = wv;
        if (tid == 0) ml_ws[b * 128 + chunk] = make_float2(mx, l);
    }
    __syncthreads();

    // context partial: c[n] = sum_{s in 64} w_s * keys[s][n]  (fp32, L2-hot)
    const int n4 = (tid & 127) << 2;
    const int sh = tid >> 7;
    const float* kctx = keys + ((size_t)(b * SS + s0 + sh * 32)) * DD + n4;
    f32x4 cacc = (f32x4){0.f, 0.f, 0.f, 0.f};
#pragma unroll 8
    for (int sI = 0; sI < 32; ++sI) {
        float wgt = w_sh[sh * 32 + sI];
        f32x4 kv  = *(const f32x4*)(kctx + (size_t)sI * DD);
        cacc += kv * wgt;
    }
    if (sh == 1) red[tid & 127] = cacc;
    __syncthreads();
    if (sh == 0) {
        cacc += red[tid];
        *(f32x4*)(cpart + ((size_t)(b * 128 + chunk)) * 512 + n4) = cacc;
    }
}

// ---------------------------------------------------------------------------
// Kernel 3: finalize.
//  blocks 0..15:    c[b][n] = (sum_i cpart[b][i][n]*exp(m_i-M)) / L
//  blocks 16..143:  a[b][s] = exp(e[b][s]-M)/L   (1024 s per block)
// ---------------------------------------------------------------------------
__global__ __launch_bounds__(256) void finalize_kernel(
    const float* __restrict__ e_ws, const float* __restrict__ cpart,
    const float2* __restrict__ ml_ws, float* __restrict__ out)
{
    __shared__ float rm[4], rs[4];
    __shared__ float sc_sh[128];
    const int bid = blockIdx.x, t = threadIdx.x;
    const int b = (bid < 16) ? bid : ((bid - 16) >> 3);

    // global M, L over this b's 128 chunk stats
    float mi = -3.402823466e38f, li = 0.0f;
    if (t < 128) { float2 p = ml_ws[b * 128 + t]; mi = p.x; li = p.y; }
    float mr = mi;
#pragma unroll
    for (int off = 32; off >= 1; off >>= 1) mr = fmaxf(mr, __shfl_xor(mr, off, 64));
    if ((t & 63) == 0) rm[t >> 6] = mr;
    __syncthreads();
    const float M = fmaxf(fmaxf(rm[0], rm[1]), fmaxf(rm[2], rm[3]));
    float si = (t < 128) ? li * __expf(mi - M) : 0.0f;
#pragma unroll
    for (int off = 32; off >= 1; off >>= 1) si += __shfl_xor(si, off, 64);
    if ((t & 63) == 0) rs[t >> 6] = si;
    __syncthreads();
    const float L = rs[0] + rs[1] + rs[2] + rs[3];
    const float invL = 1.0f / L;

    if (bid < 16) {
        if (t < 128) sc_sh[t] = __expf(ml_ws[b * 128 + t].x - M);
        __syncthreads();
        const int n0 = t * 2;
        float a0 = 0.0f, a1 = 0.0f;
#pragma unroll 4
        for (int i = 0; i < 128; ++i) {
            const float sc = sc_sh[i];
            const float* cp = cpart + ((size_t)(b * 128 + i)) * 512 + n0;
            a0 = fmaf(cp[0], sc, a0);
            a1 = fmaf(cp[1], sc, a1);
        }
        out[b * DD + n0]     = a0 * invL;
        out[b * DD + n0 + 1] = a1 * invL;
    } else {
        const int chunk8 = (bid - 16) & 7;
        const float* ep = e_ws + (size_t)b * SS + chunk8 * 1024;
        float* ap = out + BB * DD + (size_t)b * SS + chunk8 * 1024;
#pragma unroll
        for (int r = 0; r < 4; ++r) {
            float e = ep[t + 256 * r];
            ap[t + 256 * r] = __expf(e - M) * invL;
        }
    }
}

// ---------------------------------------------------------------------------
extern "C" void kernel_launch(void* const* d_in, const int* in_sizes, int n_in,
                              void* d_out, int out_size, void* d_ws, size_t ws_size,
                              hipStream_t stream)
{
    const float* query = (const float*)d_in[0];
    const float* keys  = (const float*)d_in[1];
    const int*   mask  = (const int*)  d_in[2];
    const float* Wq    = (const float*)d_in[3];
    const float* Wk    = (const float*)d_in[4];
    const float* v     = (const float*)d_in[5];
    float* out = (float*)d_out;

    // workspace layout
    float*          qproj = (float*)d_ws;                                     // 32 KB
    unsigned short* WkT   = (unsigned short*)((char*)d_ws + 32768);           // 512 KB
    float*          e_ws  = (float*)((char*)d_ws + 32768 + 524288);           // 512 KB
    float*          cpart = (float*)((char*)d_ws + 32768 + 2 * 524288);       // 4 MB
    float2*         ml_ws = (float2*)((char*)d_ws + 32768 + 2 * 524288 + 4194304); // 16 KB

    prep_kernel    <<<DD + 32, 256, 0, stream>>>(query, Wq, Wk, qproj, WkT);
    fused_kernel   <<<BB * (SS / 64), 256, 0, stream>>>(keys, WkT, qproj, v, mask,
                                                        e_ws, cpart, ml_ws);
    finalize_kernel<<<16 + 128, 256, 0, stream>>>(e_ws, cpart, ml_ws, out);
}

// Round 4
// 538.016 us; speedup vs baseline: 1.0416x; 1.0416x over previous
//
#include <hip/hip_runtime.h>

// Problem constants
#define BB 16
#define SS 8192
#define DD 512   // Q_DIM == K_DIM == ATTN_DIM

typedef float  f32x4  __attribute__((ext_vector_type(4)));
typedef __bf16 bf16x8 __attribute__((ext_vector_type(8)));
typedef __bf16 bf16x4 __attribute__((ext_vector_type(4)));

__device__ __forceinline__ void cvt_store_bf4(unsigned short* dst, f32x4 v) {
    bf16x4 o;
    o.x = (__bf16)v.x; o.y = (__bf16)v.y; o.z = (__bf16)v.z; o.w = (__bf16)v.w;
    *(bf16x4*)dst = o;   // 8-byte LDS store
}

__device__ __forceinline__ float tanh_fast(float x) {
    float e2 = __expf(2.0f * x);
    return 1.0f - 2.0f / (e2 + 1.0f);   // -> +/-1 correctly as e2 -> inf/0
}

// ---------------------------------------------------------------------------
// Kernel 1: blocks 0..63: WkT[n][k] = bf16(Wk[k][n]) via coalesced LDS transpose
//           blocks 64..95: qproj = query @ Wq (fp32), one output per thread
// ---------------------------------------------------------------------------
__global__ __launch_bounds__(256) void prep_kernel(
    const float* __restrict__ query, const float* __restrict__ Wq,
    const float* __restrict__ Wk, float* __restrict__ qproj,
    unsigned short* __restrict__ WkT)
{
    __shared__ __bf16 lt[64][65];
    const int bid = blockIdx.x, t = threadIdx.x;
    if (bid < 64) {                        // 8x8 grid of 64x64 tiles
        const int k0 = (bid >> 3) * 64, n0 = (bid & 7) * 64;
#pragma unroll
        for (int rep = 0; rep < 4; ++rep) {       // coalesced read: 256B per 16-thread row
            const int k = rep * 16 + (t >> 4), n = (t & 15) * 4;
            f32x4 vv = *(const f32x4*)&Wk[(size_t)(k0 + k) * DD + n0 + n];
            lt[k][n] = (__bf16)vv.x; lt[k][n + 1] = (__bf16)vv.y;
            lt[k][n + 2] = (__bf16)vv.z; lt[k][n + 3] = (__bf16)vv.w;
        }
        __syncthreads();
#pragma unroll
        for (int rep = 0; rep < 4; ++rep) {       // coalesced write: 128B per 16-thread row
            const int n = rep * 16 + (t >> 4), k = (t & 15) * 4;
            bf16x4 o;
            o.x = lt[k][n]; o.y = lt[k + 1][n]; o.z = lt[k + 2][n]; o.w = lt[k + 3][n];
            *(bf16x4*)&WkT[(size_t)(n0 + n) * DD + k0 + k] = o;
        }
    } else {                               // qproj: 8192 outputs, one per thread
        const int idx = (bid - 64) * 256 + t;
        const int b = idx >> 9;
        const int n = idx & 511;
        const float* q  = query + b * DD;
        const float* wp = Wq + n;
        float acc = 0.0f;
#pragma unroll 8
        for (int k = 0; k < DD; ++k)
            acc = fmaf(q[k], wp[(size_t)k * DD], acc);
        qproj[b * DD + n] = acc;
    }
}

// ---------------------------------------------------------------------------
// Kernel 2 (fused): scores + block-local softmax stats + context partial.
// 512 threads / 8 waves; each wave owns a 64-wide n-slice (acc 4x4 = 64 VGPR).
// Keys tile (64x512) staged to LDS once in bf16 fragment-major; B fragments
// loaded straight from L2-resident WkT; barrier-free K-loop.
// __launch_bounds__(512,4): 4 waves/SIMD -> 2 blocks/CU -> 16 waves/CU.
// ---------------------------------------------------------------------------
__global__ __launch_bounds__(512, 4) void fused_kernel(
    const float* __restrict__ keys, const unsigned short* __restrict__ WkT,
    const float* __restrict__ qproj, const float* __restrict__ vvec,
    const int* __restrict__ mask, float* __restrict__ e_ws,
    float* __restrict__ cpart, float2* __restrict__ ml_ws)
{
    __shared__ unsigned short ksA[16 * 2048];     // [j][i-tile][lane][8] = 64 KB
    __shared__ float sm_part[8][64];
    __shared__ float w_sh[64];
    __shared__ f32x4 red[3][128];

    const int tid  = threadIdx.x;
    const int w    = tid >> 6;        // wave 0..7 -> n slice [64w, 64w+64)
    const int lane = tid & 63;
    const int ml   = lane & 15;
    const int quad = lane >> 4;
    const int bid  = blockIdx.x;
    const int b    = bid >> 7;
    const int chunk = bid & 127;
    const int s0   = chunk << 6;

    // --- stage keys tile (64 rows x 512 k) fp32 -> bf16, fragment-major, ONCE ---
    // thread t: row m = t>>3, float4 #(t&7) of each 32-k chunk (one per j)
    const int m  = tid >> 3;
    const int q8 = tid & 7;
    const float* krow = keys + ((size_t)(b * SS + s0 + m)) * DD + q8 * 4;
    const int it = m >> 4;
    const int sq = q8 >> 1;
    const int j0 = (q8 & 1) * 4;
    const int base = it * 512 + ((m & 15) + 16 * sq) * 8 + j0;
#pragma unroll 8
    for (int j = 0; j < 16; ++j) {
        f32x4 kv = *(const f32x4*)(krow + j * 32);
        cvt_store_bf4(&ksA[j * 2048 + base], kv);
    }
    __syncthreads();

    // --- barrier-free K loop ---
    const unsigned short* wb = WkT + (size_t)(w * 64 + ml) * DD + quad * 8;

    f32x4 acc[4][4];
#pragma unroll
    for (int i = 0; i < 4; ++i)
#pragma unroll
        for (int jn = 0; jn < 4; ++jn) acc[i][jn] = (f32x4){0.f, 0.f, 0.f, 0.f};

#pragma unroll 4
    for (int j = 0; j < 16; ++j) {
        bf16x8 af[4];
#pragma unroll
        for (int i = 0; i < 4; ++i)
            af[i] = *(const bf16x8*)&ksA[j * 2048 + (i * 64 + lane) * 8];
#pragma unroll
        for (int jn = 0; jn < 4; ++jn) {
            bf16x8 bfr = *(const bf16x8*)(wb + (size_t)jn * 16 * DD + j * 32);
#pragma unroll
            for (int i = 0; i < 4; ++i)
                acc[i][jn] = __builtin_amdgcn_mfma_f32_16x16x32_bf16(af[i], bfr, acc[i][jn], 0, 0, 0);
        }
    }

    // epilogue: e-partials.  C layout: row = quad*4 + reg, col = ml
    float qv[4], vv[4];
#pragma unroll
    for (int jn = 0; jn < 4; ++jn) {
        const int n = w * 64 + jn * 16 + ml;
        qv[jn] = qproj[b * DD + n];
        vv[jn] = vvec[n];
    }
#pragma unroll
    for (int i = 0; i < 4; ++i) {
#pragma unroll
        for (int r = 0; r < 4; ++r) {
            float s = 0.0f;
#pragma unroll
            for (int jn = 0; jn < 4; ++jn) {
                float xx = acc[i][jn][r] + qv[jn];
                s += tanh_fast(xx) * vv[jn];
            }
            s += __shfl_xor(s, 1, 64);
            s += __shfl_xor(s, 2, 64);
            s += __shfl_xor(s, 4, 64);
            s += __shfl_xor(s, 8, 64);
            if (ml == 0) sm_part[w][i * 16 + quad * 4 + r] = s;
        }
    }
    __syncthreads();

    // block-local softmax stats (one wave: tid < 64, each thread one s-row)
    if (tid < 64) {
        float e = sm_part[0][tid] + sm_part[1][tid] + sm_part[2][tid] + sm_part[3][tid]
                + sm_part[4][tid] + sm_part[5][tid] + sm_part[6][tid] + sm_part[7][tid];
        const int mk = mask[b * SS + s0 + tid];
        if (mk == 0) e = -3.402823466e38f;
        e_ws[(size_t)b * SS + s0 + tid] = e;
        float mx = e;
#pragma unroll
        for (int off = 32; off >= 1; off >>= 1) mx = fmaxf(mx, __shfl_xor(mx, off, 64));
        float wv = (mk == 0) ? 0.0f : __expf(e - mx);
        float l  = wv;
#pragma unroll
        for (int off = 32; off >= 1; off >>= 1) l += __shfl_xor(l, off, 64);
        w_sh[tid] = wv;
        if (tid == 0) ml_ws[b * 128 + chunk] = make_float2(mx, l);
    }
    __syncthreads();

    // context partial: c[n] = sum_{s in 64} w_s * keys[s][n]  (fp32, L2/L3-hot)
    const int n4 = (tid & 127) << 2;
    const int sh = tid >> 7;                    // 0..3, 16 s-rows each
    const float* kctx = keys + ((size_t)(b * SS + s0 + sh * 16)) * DD + n4;
    f32x4 cacc = (f32x4){0.f, 0.f, 0.f, 0.f};
#pragma unroll 8
    for (int sI = 0; sI < 16; ++sI) {
        float wgt = w_sh[sh * 16 + sI];
        f32x4 kv  = *(const f32x4*)(kctx + (size_t)sI * DD);
        cacc += kv * wgt;
    }
    if (sh) red[sh - 1][tid & 127] = cacc;
    __syncthreads();
    if (sh == 0) {
        cacc += red[0][tid] + red[1][tid] + red[2][tid];
        *(f32x4*)(cpart + ((size_t)(b * 128 + chunk)) * 512 + n4) = cacc;
    }
}

// ---------------------------------------------------------------------------
// Kernel 3: finalize.
//  blocks 0..15:    c[b][n] = (sum_i cpart[b][i][n]*exp(m_i-M)) / L
//  blocks 16..143:  a[b][s] = exp(e[b][s]-M)/L   (1024 s per block)
// ---------------------------------------------------------------------------
__global__ __launch_bounds__(256) void finalize_kernel(
    const float* __restrict__ e_ws, const float* __restrict__ cpart,
    const float2* __restrict__ ml_ws, float* __restrict__ out)
{
    __shared__ float rm[4], rs[4];
    __shared__ float sc_sh[128];
    __shared__ float cred[4][512];
    const int bid = blockIdx.x, t = threadIdx.x;
    const int b = (bid < 16) ? bid : ((bid - 16) >> 3);

    // global M, L over this b's 128 chunk stats
    float mi = -3.402823466e38f, li = 0.0f;
    if (t < 128) { float2 p = ml_ws[b * 128 + t]; mi = p.x; li = p.y; }
    float mr = mi;
#pragma unroll
    for (int off = 32; off >= 1; off >>= 1) mr = fmaxf(mr, __shfl_xor(mr, off, 64));
    if ((t & 63) == 0) rm[t >> 6] = mr;
    __syncthreads();
    const float M = fmaxf(fmaxf(rm[0], rm[1]), fmaxf(rm[2], rm[3]));
    float si = (t < 128) ? li * __expf(mi - M) : 0.0f;
#pragma unroll
    for (int off = 32; off >= 1; off >>= 1) si += __shfl_xor(si, off, 64);
    if ((t & 63) == 0) rs[t >> 6] = si;
    __syncthreads();
    const float L = rs[0] + rs[1] + rs[2] + rs[3];
    const float invL = 1.0f / L;

    if (bid < 16) {
        if (t < 128) sc_sh[t] = __expf(ml_ws[b * 128 + t].x - M);
        __syncthreads();
        // 4 waves split the 128 i-chunks; lane l covers n = 8l..8l+8
        const int w2 = t >> 6, l = t & 63;
        float pa[8] = {0.f, 0.f, 0.f, 0.f, 0.f, 0.f, 0.f, 0.f};
#pragma unroll 4
        for (int i = w2 * 32; i < w2 * 32 + 32; ++i) {
            const float sc = sc_sh[i];
            const float* cp = cpart + ((size_t)(b * 128 + i)) * 512 + l * 8;
#pragma unroll
            for (int c = 0; c < 8; ++c) pa[c] = fmaf(cp[c], sc, pa[c]);
        }
#pragma unroll
        for (int c = 0; c < 8; ++c) cred[w2][l * 8 + c] = pa[c];
        __syncthreads();
#pragma unroll
        for (int rep = 0; rep < 2; ++rep) {
            const int n = t + rep * 256;
            out[b * DD + n] = (cred[0][n] + cred[1][n] + cred[2][n] + cred[3][n]) * invL;
        }
    } else {
        const int chunk8 = (bid - 16) & 7;
        const float* ep = e_ws + (size_t)b * SS + chunk8 * 1024;
        float* ap = out + BB * DD + (size_t)b * SS + chunk8 * 1024;
#pragma unroll
        for (int r = 0; r < 4; ++r) {
            float e = ep[t + 256 * r];
            ap[t + 256 * r] = __expf(e - M) * invL;
        }
    }
}

// ---------------------------------------------------------------------------
extern "C" void kernel_launch(void* const* d_in, const int* in_sizes, int n_in,
                              void* d_out, int out_size, void* d_ws, size_t ws_size,
                              hipStream_t stream)
{
    const float* query = (const float*)d_in[0];
    const float* keys  = (const float*)d_in[1];
    const int*   mask  = (const int*)  d_in[2];
    const float* Wq    = (const float*)d_in[3];
    const float* Wk    = (const float*)d_in[4];
    const float* v     = (const float*)d_in[5];
    float* out = (float*)d_out;

    // workspace layout
    float*          qproj = (float*)d_ws;                                     // 32 KB
    unsigned short* WkT   = (unsigned short*)((char*)d_ws + 32768);           // 512 KB
    float*          e_ws  = (float*)((char*)d_ws + 32768 + 524288);           // 512 KB
    float*          cpart = (float*)((char*)d_ws + 32768 + 2 * 524288);       // 4 MB
    float2*         ml_ws = (float2*)((char*)d_ws + 32768 + 2 * 524288 + 4194304); // 16 KB

    prep_kernel    <<<96, 256, 0, stream>>>(query, Wq, Wk, qproj, WkT);
    fused_kernel   <<<BB * (SS / 64), 512, 0, stream>>>(keys, WkT, qproj, v, mask,
                                                        e_ws, cpart, ml_ws);
    finalize_kernel<<<16 + 128, 256, 0, stream>>>(e_ws, cpart, ml_ws, out);
}

// Round 5
// 486.121 us; speedup vs baseline: 1.1527x; 1.1068x over previous
//
#include <hip/hip_runtime.h>

// Problem constants
#define BB 16
#define SS 8192
#define DD 512   // Q_DIM == K_DIM == ATTN_DIM

typedef float  f32x4  __attribute__((ext_vector_type(4)));
typedef __bf16 bf16x8 __attribute__((ext_vector_type(8)));
typedef __bf16 bf16x4 __attribute__((ext_vector_type(4)));

__device__ __forceinline__ void cvt_store_bf4(unsigned short* dst, f32x4 v) {
    bf16x4 o;
    o.x = (__bf16)v.x; o.y = (__bf16)v.y; o.z = (__bf16)v.z; o.w = (__bf16)v.w;
    *(bf16x4*)dst = o;   // 8-byte LDS store
}

__device__ __forceinline__ float tanh_fast(float x) {
    float e2 = __expf(2.0f * x);
    return 1.0f - 2.0f / (e2 + 1.0f);   // -> +/-1 correctly as e2 -> inf/0
}

// ---------------------------------------------------------------------------
// Kernel 1: blocks 0..63: WkT_f = bf16(Wk^T) in MFMA-fragment order:
//   element (n,k) -> WkT_f[ ((g*16 + j)*64 + lane)*8 + d ]
//   g=n>>4, ml=n&15, j=k>>5, quad=(k>>3)&3, d=k&7, lane=quad*16+ml
//   => each wave B-load (fixed g,j) reads a CONTIGUOUS 1 KB block.
// blocks 64..95: qproj = query @ Wq (fp32), one output per thread
// ---------------------------------------------------------------------------
__global__ __launch_bounds__(256) void prep_kernel(
    const float* __restrict__ query, const float* __restrict__ Wq,
    const float* __restrict__ Wk, float* __restrict__ qproj,
    unsigned short* __restrict__ WkT_f)
{
    __shared__ __bf16 lt[64][65];
    const int bid = blockIdx.x, t = threadIdx.x;
    if (bid < 64) {                        // 8x8 grid of 64x64 (k,n) tiles
        const int k0 = (bid >> 3) * 64, n0 = (bid & 7) * 64;
#pragma unroll
        for (int rep = 0; rep < 4; ++rep) {       // coalesced read
            const int k = rep * 16 + (t >> 4), n = (t & 15) * 4;
            f32x4 vv = *(const f32x4*)&Wk[(size_t)(k0 + k) * DD + n0 + n];
            lt[k][n] = (__bf16)vv.x; lt[k][n + 1] = (__bf16)vv.y;
            lt[k][n + 2] = (__bf16)vv.z; lt[k][n + 3] = (__bf16)vv.w;
        }
        __syncthreads();
        // write fragment-major: thread = (g_loc = t>>6, lane = t&63)
        const int g_loc = t >> 6, lane = t & 63;
        const int ml = lane & 15, quad = lane >> 4;
        const int g = (bid & 7) * 4 + g_loc;
#pragma unroll
        for (int j_loc = 0; j_loc < 2; ++j_loc) {
            const int j = (bid >> 3) * 2 + j_loc;
            bf16x8 o;
#pragma unroll
            for (int d = 0; d < 8; ++d)
                o[d] = lt[j_loc * 32 + quad * 8 + d][g_loc * 16 + ml];
            *(bf16x8*)&WkT_f[((size_t)((g * 16 + j) * 64 + lane)) * 8] = o;
        }
    } else {                               // qproj: 8192 outputs, one per thread
        const int idx = (bid - 64) * 256 + t;
        const int b = idx >> 9;
        const int n = idx & 511;
        const float* q  = query + b * DD;
        const float* wp = Wq + n;
        float acc = 0.0f;
#pragma unroll 8
        for (int k = 0; k < DD; ++k)
            acc = fmaf(q[k], wp[(size_t)k * DD], acc);
        qproj[b * DD + n] = acc;
    }
}

// ---------------------------------------------------------------------------
// Kernel 2 (fused): scores + block-local softmax stats + context partial.
// 512 threads / 8 waves; wave w owns n-slice [64w, 64w+64).
// Staging: 8 batched in-flight f32x4 loads -> cvt -> LDS (fragment-major).
// K-loop barrier-free: A from LDS, B from L2-resident WkT_f (contiguous 1KB).
// ---------------------------------------------------------------------------
__global__ __launch_bounds__(512, 4) void fused_kernel(
    const float* __restrict__ keys, const unsigned short* __restrict__ WkT_f,
    const float* __restrict__ qproj, const float* __restrict__ vvec,
    const int* __restrict__ mask, float* __restrict__ e_ws,
    float* __restrict__ cpart, float2* __restrict__ ml_ws)
{
    __shared__ unsigned short ksA[16 * 2048];     // [j][i-tile][lane][8] = 64 KB
    __shared__ float sm_part[8][64];
    __shared__ float w_sh[64];
    __shared__ f32x4 red[3][128];

    const int tid  = threadIdx.x;
    const int w    = tid >> 6;        // wave 0..7
    const int lane = tid & 63;
    const int ml   = lane & 15;
    const int quad = lane >> 4;
    const int bid  = blockIdx.x;
    const int b    = bid >> 7;
    const int chunk = bid & 127;
    const int s0   = chunk << 6;

    // --- stage keys tile (64 rows x 512 k) fp32 -> bf16, fragment-major ---
    // thread t: row m = t>>3, float4 #(t&7) of each 32-k chunk (one per j)
    const int m  = tid >> 3;
    const int q8 = tid & 7;
    const float* krow = keys + ((size_t)(b * SS + s0 + m)) * DD + q8 * 4;
    const int it = m >> 4;
    const int sq = q8 >> 1;
    const int j0 = (q8 & 1) * 4;
    const int base = it * 512 + ((m & 15) + 16 * sq) * 8 + j0;
    {
        f32x4 kst[8];
#pragma unroll
        for (int h = 0; h < 2; ++h) {
#pragma unroll
            for (int j = 0; j < 8; ++j)            // 8 independent loads in flight
                kst[j] = *(const f32x4*)(krow + (h * 8 + j) * 32);
#pragma unroll
            for (int j = 0; j < 8; ++j)
                cvt_store_bf4(&ksA[(h * 8 + j) * 2048 + base], kst[j]);
        }
    }
    __syncthreads();

    // --- barrier-free K loop; B contiguous per-wave from WkT_f ---
    const unsigned short* wfb = WkT_f + (size_t)w * 32768 + lane * 8;

    f32x4 acc[4][4];
#pragma unroll
    for (int i = 0; i < 4; ++i)
#pragma unroll
        for (int jn = 0; jn < 4; ++jn) acc[i][jn] = (f32x4){0.f, 0.f, 0.f, 0.f};

#pragma unroll 4
    for (int j = 0; j < 16; ++j) {
        bf16x8 af[4];
#pragma unroll
        for (int i = 0; i < 4; ++i)
            af[i] = *(const bf16x8*)&ksA[j * 2048 + (i * 64 + lane) * 8];
#pragma unroll
        for (int jn = 0; jn < 4; ++jn) {
            bf16x8 bfr = *(const bf16x8*)(wfb + ((jn * 16 + j) << 9));
#pragma unroll
            for (int i = 0; i < 4; ++i)
                acc[i][jn] = __builtin_amdgcn_mfma_f32_16x16x32_bf16(af[i], bfr, acc[i][jn], 0, 0, 0);
        }
    }

    // epilogue: e-partials.  C layout: row = quad*4 + reg, col = ml
    float qv[4], vv[4];
#pragma unroll
    for (int jn = 0; jn < 4; ++jn) {
        const int n = w * 64 + jn * 16 + ml;
        qv[jn] = qproj[b * DD + n];
        vv[jn] = vvec[n];
    }
#pragma unroll
    for (int i = 0; i < 4; ++i) {
#pragma unroll
        for (int r = 0; r < 4; ++r) {
            float s = 0.0f;
#pragma unroll
            for (int jn = 0; jn < 4; ++jn) {
                float xx = acc[i][jn][r] + qv[jn];
                s += tanh_fast(xx) * vv[jn];
            }
            s += __shfl_xor(s, 1, 64);
            s += __shfl_xor(s, 2, 64);
            s += __shfl_xor(s, 4, 64);
            s += __shfl_xor(s, 8, 64);
            if (ml == 0) sm_part[w][i * 16 + quad * 4 + r] = s;
        }
    }
    __syncthreads();

    // block-local softmax stats (one wave: tid < 64, each thread one s-row)
    if (tid < 64) {
        float e = sm_part[0][tid] + sm_part[1][tid] + sm_part[2][tid] + sm_part[3][tid]
                + sm_part[4][tid] + sm_part[5][tid] + sm_part[6][tid] + sm_part[7][tid];
        const int mk = mask[b * SS + s0 + tid];
        if (mk == 0) e = -3.402823466e38f;
        e_ws[(size_t)b * SS + s0 + tid] = e;
        float mx = e;
#pragma unroll
        for (int off = 32; off >= 1; off >>= 1) mx = fmaxf(mx, __shfl_xor(mx, off, 64));
        float wv = (mk == 0) ? 0.0f : __expf(e - mx);
        float l  = wv;
#pragma unroll
        for (int off = 32; off >= 1; off >>= 1) l += __shfl_xor(l, off, 64);
        w_sh[tid] = wv;
        if (tid == 0) ml_ws[b * 128 + chunk] = make_float2(mx, l);
    }
    __syncthreads();

    // context partial: c[n] = sum_{s in 64} w_s * keys[s][n]  (fp32, L2/L3-hot)
    const int n4 = (tid & 127) << 2;
    const int sh = tid >> 7;                    // 0..3, 16 s-rows each
    const float* kctx = keys + ((size_t)(b * SS + s0 + sh * 16)) * DD + n4;
    f32x4 cacc = (f32x4){0.f, 0.f, 0.f, 0.f};
#pragma unroll 8
    for (int sI = 0; sI < 16; ++sI) {
        float wgt = w_sh[sh * 16 + sI];
        f32x4 kv  = *(const f32x4*)(kctx + (size_t)sI * DD);
        cacc += kv * wgt;
    }
    if (sh) red[sh - 1][tid & 127] = cacc;
    __syncthreads();
    if (sh == 0) {
        cacc += red[0][tid] + red[1][tid] + red[2][tid];
        *(f32x4*)(cpart + ((size_t)(b * 128 + chunk)) * 512 + n4) = cacc;
    }
}

// ---------------------------------------------------------------------------
// Kernel 3: finalize.
//  blocks 0..15:    c[b][n] = (sum_i cpart[b][i][n]*exp(m_i-M)) / L
//  blocks 16..143:  a[b][s] = exp(e[b][s]-M)/L   (1024 s per block)
// ---------------------------------------------------------------------------
__global__ __launch_bounds__(256) void finalize_kernel(
    const float* __restrict__ e_ws, const float* __restrict__ cpart,
    const float2* __restrict__ ml_ws, float* __restrict__ out)
{
    __shared__ float rm[4], rs[4];
    __shared__ float sc_sh[128];
    __shared__ float cred[4][512];
    const int bid = blockIdx.x, t = threadIdx.x;
    const int b = (bid < 16) ? bid : ((bid - 16) >> 3);

    // global M, L over this b's 128 chunk stats
    float mi = -3.402823466e38f, li = 0.0f;
    if (t < 128) { float2 p = ml_ws[b * 128 + t]; mi = p.x; li = p.y; }
    float mr = mi;
#pragma unroll
    for (int off = 32; off >= 1; off >>= 1) mr = fmaxf(mr, __shfl_xor(mr, off, 64));
    if ((t & 63) == 0) rm[t >> 6] = mr;
    __syncthreads();
    const float M = fmaxf(fmaxf(rm[0], rm[1]), fmaxf(rm[2], rm[3]));
    float si = (t < 128) ? li * __expf(mi - M) : 0.0f;
#pragma unroll
    for (int off = 32; off >= 1; off >>= 1) si += __shfl_xor(si, off, 64);
    if ((t & 63) == 0) rs[t >> 6] = si;
    __syncthreads();
    const float L = rs[0] + rs[1] + rs[2] + rs[3];
    const float invL = 1.0f / L;

    if (bid < 16) {
        if (t < 128) sc_sh[t] = __expf(ml_ws[b * 128 + t].x - M);
        __syncthreads();
        // 4 waves split the 128 i-chunks; lane l covers n = 8l..8l+8
        const int w2 = t >> 6, l = t & 63;
        float pa[8] = {0.f, 0.f, 0.f, 0.f, 0.f, 0.f, 0.f, 0.f};
#pragma unroll 4
        for (int i = w2 * 32; i < w2 * 32 + 32; ++i) {
            const float sc = sc_sh[i];
            const float* cp = cpart + ((size_t)(b * 128 + i)) * 512 + l * 8;
#pragma unroll
            for (int c = 0; c < 8; ++c) pa[c] = fmaf(cp[c], sc, pa[c]);
        }
#pragma unroll
        for (int c = 0; c < 8; ++c) cred[w2][l * 8 + c] = pa[c];
        __syncthreads();
#pragma unroll
        for (int rep = 0; rep < 2; ++rep) {
            const int n = t + rep * 256;
            out[b * DD + n] = (cred[0][n] + cred[1][n] + cred[2][n] + cred[3][n]) * invL;
        }
    } else {
        const int chunk8 = (bid - 16) & 7;
        const float* ep = e_ws + (size_t)b * SS + chunk8 * 1024;
        float* ap = out + BB * DD + (size_t)b * SS + chunk8 * 1024;
#pragma unroll
        for (int r = 0; r < 4; ++r) {
            float e = ep[t + 256 * r];
            ap[t + 256 * r] = __expf(e - M) * invL;
        }
    }
}

// ---------------------------------------------------------------------------
extern "C" void kernel_launch(void* const* d_in, const int* in_sizes, int n_in,
                              void* d_out, int out_size, void* d_ws, size_t ws_size,
                              hipStream_t stream)
{
    const float* query = (const float*)d_in[0];
    const float* keys  = (const float*)d_in[1];
    const int*   mask  = (const int*)  d_in[2];
    const float* Wq    = (const float*)d_in[3];
    const float* Wk    = (const float*)d_in[4];
    const float* v     = (const float*)d_in[5];
    float* out = (float*)d_out;

    // workspace layout
    float*          qproj = (float*)d_ws;                                     // 32 KB
    unsigned short* WkT_f = (unsigned short*)((char*)d_ws + 32768);           // 512 KB
    float*          e_ws  = (float*)((char*)d_ws + 32768 + 524288);           // 512 KB
    float*          cpart = (float*)((char*)d_ws + 32768 + 2 * 524288);       // 4 MB
    float2*         ml_ws = (float2*)((char*)d_ws + 32768 + 2 * 524288 + 4194304); // 16 KB

    prep_kernel    <<<96, 256, 0, stream>>>(query, Wq, Wk, qproj, WkT_f);
    fused_kernel   <<<BB * (SS / 64), 512, 0, stream>>>(keys, WkT_f, qproj, v, mask,
                                                        e_ws, cpart, ml_ws);
    finalize_kernel<<<16 + 128, 256, 0, stream>>>(e_ws, cpart, ml_ws, out);
}